// Round 9
// baseline (237.033 us; speedup 1.0000x reference)
//
#include <hip/hip_runtime.h>

// B=8, C=256, H=W=48 -> N=2304, k=4 -> CK=64
#define BATCH 8
#define CIN   256
#define NPIX  2304
#define CKD   64
#define NIT   (NPIX / 16)  // 144 16-pixel tiles
#define NIC   (NPIX / 32)  // 72 32-i chunks
#define NJB   (NPIX / 64)  // 36 64-j blocks (energy partial granularity)

typedef _Float16 f16;
typedef __attribute__((ext_vector_type(4))) _Float16 f16x4;
typedef __attribute__((ext_vector_type(8))) _Float16 f16x8;
typedef __attribute__((ext_vector_type(4))) float    f32x4;

// Blocked layouts (tile = 512 f16 = 1KB, lane ln owns f16s ln*8..ln*8+7):
//   q_blk[b][IT][ks][512]   A-frag: pix = IT*16+(ln&15), ck = ks*32+(ln>>4)*8+m
//   k_blk[b][JT][ks][512]   B-frag, same internal structure
//   u_blk[b][CT][ic][512]   A-frag: c = CT*16+(ln&15), i = ic*32+(ln>>4)*8+m
//   o1_blk[b][JT][cc][512]  B-frag: j = JT*16+(ln&15), c = cc*32+(ln>>4)*8+m
//   Wg_blk[OT][cc][512]     A-frag: o = OT*16+(ln&15), c = cc*32+(ln>>4)*8+m

// ---------------------------------------------------------------------------
// Cast q/k/v conv weights fp32 -> f16 (flat). Wqk = [qw; kw] (128x256).
// ---------------------------------------------------------------------------
__global__ __launch_bounds__(256) void cast_w(
    const float* __restrict__ qw, const float* __restrict__ kw,
    const float* __restrict__ vw, f16* __restrict__ Wqk, f16* __restrict__ Wv)
{
    int idx = (blockIdx.x * 256 + threadIdx.x) * 4;
    const float* src;
    f16* dst;
    if (idx < 16384)      { src = qw + idx;           dst = Wqk + idx; }
    else if (idx < 32768) { src = kw + (idx - 16384); dst = Wqk + idx; }
    else                  { src = vw + (idx - 32768); dst = Wv + (idx - 32768); }
    float4 v = *(const float4*)src;
    f16x4 h = { (f16)v.x, (f16)v.y, (f16)v.z, (f16)v.w };
    *(f16x4*)dst = h;
}

// ---------------------------------------------------------------------------
// Cast gamma weight fp32 -> f16 A-frag-blocked. 8192 threads.
// ---------------------------------------------------------------------------
__global__ __launch_bounds__(256) void cast_wg(
    const float* __restrict__ gw, f16* __restrict__ Wg_blk)
{
    int tid = blockIdx.x * 256 + threadIdx.x;
    int tile = tid >> 6, ln = tid & 63;
    int o = (tile >> 3) * 16 + (ln & 15);
    int c = (tile & 7) * 32 + (ln >> 4) * 8;
    const float* src = gw + (size_t)o * CIN + c;
    float4 v0 = *(const float4*)src;
    float4 v1 = *(const float4*)(src + 4);
    f16x8 h = { (f16)v0.x, (f16)v0.y, (f16)v0.z, (f16)v0.w,
                (f16)v1.x, (f16)v1.y, (f16)v1.z, (f16)v1.w };
    *(f16x8*)&Wg_blk[(size_t)tile * 512 + ln * 8] = h;
}

// ---------------------------------------------------------------------------
// x[b][c][n] fp32 -> xT[b][n][c] f16 (LDS transpose). Tile 64c x 64n.
// ---------------------------------------------------------------------------
__global__ __launch_bounds__(256) void cast_xT(
    const float* __restrict__ x, f16* __restrict__ xT)
{
    __shared__ float s[64][65];
    const int t = threadIdx.x;
    const int n0 = blockIdx.x * 64, c0 = blockIdx.y * 64, b = blockIdx.z;
    const float* xb = x + ((size_t)b * CIN + c0) * NPIX + n0;

    const int cl = t >> 4, ng = (t & 15) * 4;
    #pragma unroll
    for (int p = 0; p < 4; ++p) {
        float4 v = *(const float4*)(xb + (size_t)(cl + 16 * p) * NPIX + ng);
        s[cl + 16 * p][ng + 0] = v.x;
        s[cl + 16 * p][ng + 1] = v.y;
        s[cl + 16 * p][ng + 2] = v.z;
        s[cl + 16 * p][ng + 3] = v.w;
    }
    __syncthreads();
    const int nl = t >> 2, cs = (t & 3) * 16;
    f16 h[16];
    #pragma unroll
    for (int j = 0; j < 16; ++j) h[j] = (f16)s[cs + j][nl];
    f16* gp = &xT[((size_t)b * NPIX + n0 + nl) * CIN + c0 + cs];
    *(f16x8*)gp       = *(f16x8*)&h[0];
    *(f16x8*)(gp + 8) = *(f16x8*)&h[8];
}

// ---------------------------------------------------------------------------
// q & k conv via MFMA; outputs q_blk / k_blk (frag-blocked) via LDS repack.
// grid (N/32, B), block 256.
// ---------------------------------------------------------------------------
__global__ __launch_bounds__(256) void qk_conv_mfma(
    const f16* __restrict__ xT, const f16* __restrict__ Wqk,
    const float* __restrict__ qbias, const float* __restrict__ kbias,
    f16* __restrict__ q_blk, f16* __restrict__ k_blk)
{
    __shared__ __align__(16) f16 us[32 * 136];   // [n_local][o]
    const int t = threadIdx.x, w = t >> 6, lane = t & 63;
    const int quad = lane >> 4, l16 = lane & 15;
    const int wm = w & 1, wn = w >> 1;
    const int n0 = blockIdx.x * 32, b = blockIdx.y;

    const f16* bp = xT + ((size_t)b * NPIX + n0 + 16 * wn + l16) * CIN;
    const f16* ap = Wqk + (size_t)(64 * wm + l16) * CIN;

    f32x4 acc[4];
    #pragma unroll
    for (int mt = 0; mt < 4; ++mt) acc[mt] = (f32x4){0.f, 0.f, 0.f, 0.f};

    #pragma unroll
    for (int kk = 0; kk < CIN; kk += 32) {
        f16x8 bf = *(const f16x8*)(bp + kk + quad * 8);
        #pragma unroll
        for (int mt = 0; mt < 4; ++mt) {
            f16x8 af = *(const f16x8*)(ap + (size_t)mt * 16 * CIN + kk + quad * 8);
            acc[mt] = __builtin_amdgcn_mfma_f32_16x16x32_f16(af, bf, acc[mt], 0, 0, 0);
        }
    }
    const float* bias = wm ? kbias - 64 : qbias;   // o-indexed
    #pragma unroll
    for (int mt = 0; mt < 4; ++mt) {
        int ob = 64 * wm + 16 * mt + quad * 4;
        #pragma unroll
        for (int r = 0; r < 4; ++r)
            us[(16 * wn + l16) * 136 + ob + r] = (f16)(acc[mt][r] + bias[ob + r]);
    }
    __syncthreads();
    {
        int ks2 = t >> 7, nt = (t >> 6) & 1, ln = t & 63;
        const f16* usr = &us[(nt * 16 + (ln & 15)) * 136 + ks2 * 32 + (ln >> 4) * 8];
        size_t base = (((size_t)b * NIT + (n0 >> 4) + nt) * 2 + ks2) * 512 + ln * 8;
        *(f16x8*)&q_blk[base] = *(const f16x8*)(usr);
        *(f16x8*)&k_blk[base] = *(const f16x8*)(usr + 64);
    }
}

// ---------------------------------------------------------------------------
// S-only energy pass: partial row sums of f16(exp(q_i.k_j)) per 64-j block.
// grid (N/64 j, N/128 i, B), block 256.
// ---------------------------------------------------------------------------
#define ESL 136
__global__ __launch_bounds__(256) void energy_S(
    const f16* __restrict__ q_blk, const f16* __restrict__ k_blk,
    float* __restrict__ Pred)
{
    __shared__ __align__(16) f16 es[64 * ESL];
    __shared__ float red2[2][128];
    const int t    = threadIdx.x;
    const int w    = t >> 6, lane = t & 63;
    const int quad = lane >> 4, l16 = lane & 15;
    const int j0 = blockIdx.x * 64, i0 = blockIdx.y * 128, b = blockIdx.z;
    const size_t ln8 = (size_t)lane * 8;
    const f16* qb = q_blk + (size_t)b * NIT * 2 * 512 + ln8;

    f32x4 acc[8];
    #pragma unroll
    for (int mt = 0; mt < 8; ++mt) acc[mt] = (f32x4){0.f, 0.f, 0.f, 0.f};

    #pragma unroll
    for (int ks = 0; ks < 2; ++ks) {
        f16x8 bf = *(const f16x8*)(k_blk +
            (((size_t)b * NIT + (j0 >> 4) + w) * 2 + ks) * 512 + ln8);
        #pragma unroll
        for (int mt = 0; mt < 8; ++mt) {
            f16x8 af = *(const f16x8*)(qb + ((size_t)((i0 >> 4) + mt) * 2 + ks) * 512);
            acc[mt] = __builtin_amdgcn_mfma_f32_16x16x32_f16(af, bf, acc[mt], 0, 0, 0);
        }
    }

    #pragma unroll
    for (int mt = 0; mt < 8; ++mt) {
        f16x4 h = { (f16)__expf(acc[mt][0]), (f16)__expf(acc[mt][1]),
                    (f16)__expf(acc[mt][2]), (f16)__expf(acc[mt][3]) };
        *(f16x4*)&es[(16 * w + l16) * ESL + 16 * mt + quad * 4] = h;
    }
    __syncthreads();
    {
        int i = t & 127, jq = t >> 7;
        float s = 0.f;
        #pragma unroll
        for (int jj = 0; jj < 32; ++jj)
            s += (float)es[(jq * 32 + jj) * ESL + i];
        red2[jq][i] = s;
    }
    __syncthreads();
    if (t < 128)
        Pred[((size_t)blockIdx.x * BATCH + b) * NPIX + i0 + t] =
            red2[0][t] + red2[1][t];
}

// ---------------------------------------------------------------------------
// S[b,i] = sum over 36 j-block partials (coalesced). grid BN/256.
// ---------------------------------------------------------------------------
__global__ __launch_bounds__(256) void reduce_S(
    const float* __restrict__ Pred, float* __restrict__ S)
{
    const size_t BN = (size_t)BATCH * NPIX;
    size_t idx = (size_t)blockIdx.x * 256 + threadIdx.x;
    float s = 0.f;
    #pragma unroll
    for (int jb = 0; jb < NJB; ++jb)
        s += Pred[(size_t)jb * BN + idx];
    S[idx] = s;
}

// ---------------------------------------------------------------------------
// v conv via MFMA, fused bias + 1/S scale; output u_blk (A-frag-blocked).
// Tile 128(c) x 64(i), BK=32. grid (N/64, C/128, B), block 256.
// ---------------------------------------------------------------------------
__global__ __launch_bounds__(256) void v_conv_mfma(
    const f16* __restrict__ xT, const f16* __restrict__ Wv,
    const float* __restrict__ vbias, const float* __restrict__ S,
    f16* __restrict__ u_blk)
{
    __shared__ __align__(16) f16 smem[9216];   // As 128*40 | Bs 64*40; reused as us 128*72
    f16* As = smem;
    f16* Bs = smem + 128 * 40;
    f16* us = smem;
    const int t = threadIdx.x, w = t >> 6, lane = t & 63;
    const int quad = lane >> 4, l16 = lane & 15;
    const int wm = w & 1, wn = w >> 1;
    const int i0 = blockIdx.x * 64, c0 = blockIdx.y * 128, b = blockIdx.z;
    const int sub = t >> 2, le = t & 3;
    const f16* srcA = Wv + (size_t)(c0 + sub) * CIN + le * 8;
    const f16* srcB = xT + ((size_t)b * NPIX + i0 + sub) * CIN + le * 8;
    const int ldsw = sub * 40 + le * 8;

    f32x4 acc[4][2];
    #pragma unroll
    for (int mt = 0; mt < 4; ++mt)
        #pragma unroll
        for (int nt = 0; nt < 2; ++nt)
            acc[mt][nt] = (f32x4){0.f, 0.f, 0.f, 0.f};

    for (int kk = 0; kk < CIN; kk += 32) {
        f16x8 ta0 = *(const f16x8*)(srcA + kk);
        f16x8 ta1 = *(const f16x8*)(srcA + (size_t)64 * CIN + kk);
        f16x8 tb0 = *(const f16x8*)(srcB + kk);
        __syncthreads();
        *(f16x8*)&As[ldsw]           = ta0;
        *(f16x8*)&As[64 * 40 + ldsw] = ta1;
        *(f16x8*)&Bs[ldsw]           = tb0;
        __syncthreads();
        f16x8 af[4], bf[2];
        #pragma unroll
        for (int mt = 0; mt < 4; ++mt)
            af[mt] = *(const f16x8*)&As[(64 * wm + 16 * mt + l16) * 40 + quad * 8];
        #pragma unroll
        for (int nt = 0; nt < 2; ++nt)
            bf[nt] = *(const f16x8*)&Bs[(32 * wn + 16 * nt + l16) * 40 + quad * 8];
        #pragma unroll
        for (int mt = 0; mt < 4; ++mt)
            #pragma unroll
            for (int nt = 0; nt < 2; ++nt)
                acc[mt][nt] = __builtin_amdgcn_mfma_f32_16x16x32_f16(
                    af[mt], bf[nt], acc[mt][nt], 0, 0, 0);
    }

    __syncthreads();   // As/Bs dead; reuse as us[c][i] (stride 72)
    #pragma unroll
    for (int nt = 0; nt < 2; ++nt) {
        int i = 32 * wn + 16 * nt + l16;
        float is = 1.0f / S[(size_t)b * NPIX + i0 + i];
        #pragma unroll
        for (int mt = 0; mt < 4; ++mt)
            #pragma unroll
            for (int r = 0; r < 4; ++r) {
                int c = 64 * wm + 16 * mt + quad * 4 + r;
                us[c * 72 + i] = (f16)((acc[mt][nt][r] + vbias[c0 + c]) * is);
            }
    }
    __syncthreads();
    #pragma unroll
    for (int p = 0; p < 4; ++p) {
        int g  = t + 256 * p;
        int ct = g >> 7, ic = (g >> 6) & 1, ln = g & 63;
        f16x8 v = *(const f16x8*)&us[(ct * 16 + (ln & 15)) * 72 + ic * 32 + (ln >> 4) * 8];
        *(f16x8*)&u_blk[(((size_t)b * 16 + (c0 >> 4) + ct) * NIC + (i0 >> 5) + ic) * 512 + ln * 8] = v;
    }
}

// ---------------------------------------------------------------------------
// FUSED bmm: o1[j,c] = sum_i u[c,i] * f16(exp(q_i.k_j))
// Block 32j x 128c, 4 waves; grid (72, 2, 8) = 1152 blocks (4.5/CU).
// Per 128-i chunk (18 iters):
//  stage1: wave w (jt=w>>1, i-half=w&1): E 64i x 16j = 8 MFMA -> exp -> es
//  stage2: each wave: 2 c-tiles x 2 jt x 4 isub = 16 MFMA (u direct-global)
// q-frags double-buffered: next iter's 8 loads issue before stage2.
// Epilogue: LDS transpose -> o1_blk (B-frag-blocked for gamma).
// ---------------------------------------------------------------------------
__global__ __launch_bounds__(256) void fused_bmm(
    const f16* __restrict__ q_blk, const f16* __restrict__ k_blk,
    const f16* __restrict__ u_blk, f16* __restrict__ o1_blk)
{
    __shared__ __align__(16) f16 es[32 * 136];   // [j_local][i_chunk 128 + pad]
    const int t = threadIdx.x, w = t >> 6, lane = t & 63;
    const int quad = lane >> 4, l16 = lane & 15;
    const int j0 = blockIdx.x * 32;
    const int ch = blockIdx.y, b = blockIdx.z;
    const int jtl = w >> 1, ih = w & 1;
    const size_t ln8 = (size_t)lane * 8;

    const f16* qb = q_blk + (size_t)b * NIT * 2 * 512 + ln8;
    const f16* ub = u_blk + (size_t)b * 16 * NIC * 512 + ln8;

    // k-frags for this wave's stage-1 j-strip, resident all kernel
    f16x8 kf[2];
    #pragma unroll
    for (int ks = 0; ks < 2; ++ks)
        kf[ks] = *(const f16x8*)(k_blk +
            (((size_t)b * NIT + (j0 >> 4) + jtl) * 2 + ks) * 512 + ln8);

    const int CT0 = ch * 8 + w * 2;

    f32x4 acc[2][2];
    #pragma unroll
    for (int mt = 0; mt < 2; ++mt)
        #pragma unroll
        for (int jt = 0; jt < 2; ++jt)
            acc[mt][jt] = (f32x4){0.f, 0.f, 0.f, 0.f};

    f16x8 qfA[4][2], qfB[4][2];
    #pragma unroll
    for (int it = 0; it < 4; ++it)
        #pragma unroll
        for (int ks = 0; ks < 2; ++ks)
            qfA[it][ks] = *(const f16x8*)(qb + ((size_t)(ih * 4 + it) * 2 + ks) * 512);

    auto body = [&](int ic, f16x8 (&cur)[4][2], f16x8 (&nxt)[4][2]) {
        // stage 1: E (i-half 64) x (16 j)
        f32x4 e[4];
        #pragma unroll
        for (int it = 0; it < 4; ++it) e[it] = (f32x4){0.f, 0.f, 0.f, 0.f};
        #pragma unroll
        for (int ks = 0; ks < 2; ++ks)
            #pragma unroll
            for (int it = 0; it < 4; ++it)
                e[it] = __builtin_amdgcn_mfma_f32_16x16x32_f16(
                    cur[it][ks], kf[ks], e[it], 0, 0, 0);
        __syncthreads();   // prior stage-2 es reads complete
        #pragma unroll
        for (int it = 0; it < 4; ++it) {
            f16x4 h = { (f16)__expf(e[it][0]), (f16)__expf(e[it][1]),
                        (f16)__expf(e[it][2]), (f16)__expf(e[it][3]) };
            *(f16x4*)&es[(jtl * 16 + l16) * 136 + ih * 64 + it * 16 + quad * 4] = h;
        }
        __syncthreads();
        // prefetch next iter's q-frags (overlaps stage-2 MFMA)
        if (ic + 1 < NPIX / 128)
            #pragma unroll
            for (int it = 0; it < 4; ++it)
                #pragma unroll
                for (int ks = 0; ks < 2; ++ks)
                    nxt[it][ks] = *(const f16x8*)(qb +
                        ((size_t)((ic + 1) * 8 + ih * 4 + it) * 2 + ks) * 512);
        // stage 2
        #pragma unroll
        for (int isub = 0; isub < 4; ++isub) {
            f16x8 bf0 = *(const f16x8*)&es[(l16) * 136 + isub * 32 + quad * 8];
            f16x8 bf1 = *(const f16x8*)&es[(16 + l16) * 136 + isub * 32 + quad * 8];
            f16x8 a0 = *(const f16x8*)(ub + ((size_t)(CT0 + 0) * NIC + ic * 4 + isub) * 512);
            f16x8 a1 = *(const f16x8*)(ub + ((size_t)(CT0 + 1) * NIC + ic * 4 + isub) * 512);
            acc[0][0] = __builtin_amdgcn_mfma_f32_16x16x32_f16(a0, bf0, acc[0][0], 0, 0, 0);
            acc[0][1] = __builtin_amdgcn_mfma_f32_16x16x32_f16(a0, bf1, acc[0][1], 0, 0, 0);
            acc[1][0] = __builtin_amdgcn_mfma_f32_16x16x32_f16(a1, bf0, acc[1][0], 0, 0, 0);
            acc[1][1] = __builtin_amdgcn_mfma_f32_16x16x32_f16(a1, bf1, acc[1][1], 0, 0, 0);
        }
    };

    for (int ic = 0; ic < NPIX / 128; ic += 2) {
        body(ic, qfA, qfB);
        body(ic + 1, qfB, qfA);
    }

    // epilogue: acc -> us[j][c_local] -> blocked o1 store
    __syncthreads();
    f16* us = es;
    #pragma unroll
    for (int mt = 0; mt < 2; ++mt)
        #pragma unroll
        for (int jt = 0; jt < 2; ++jt) {
            f16x4 h = { (f16)acc[mt][jt][0], (f16)acc[mt][jt][1],
                        (f16)acc[mt][jt][2], (f16)acc[mt][jt][3] };
            *(f16x4*)&us[(jt * 16 + l16) * 136 + w * 32 + mt * 16 + quad * 4] = h;
        }
    __syncthreads();
    #pragma unroll
    for (int p = 0; p < 2; ++p) {
        int g = t + 256 * p;
        int tile = g >> 6, ln = g & 63;
        int jt2 = tile >> 2, ccl = tile & 3;
        f16x8 v = *(const f16x8*)&us[(jt2 * 16 + (ln & 15)) * 136 + ccl * 32 + (ln >> 4) * 8];
        *(f16x8*)&o1_blk[(((size_t)b * NIT + (j0 >> 4) + jt2) * 8 + ch * 4 + ccl) * 512 + ln * 8] = v;
    }
}

// ---------------------------------------------------------------------------
// Gamma conv: streaming MFMA, no LDS/barriers. A = Wg_blk, B = o1_blk.
// Block 64j x 128o, 4 waves (wave jt=w). grid (36, 2, 8).
// ---------------------------------------------------------------------------
__global__ __launch_bounds__(256) void gamma_conv_mfma(
    const f16* __restrict__ o1_blk, const f16* __restrict__ Wg_blk,
    const float* __restrict__ gbias, float* __restrict__ out)
{
    const int t = threadIdx.x, w = t >> 6, lane = t & 63;
    const int quad = lane >> 4, l16 = lane & 15;
    const int j0 = blockIdx.x * 64, oh = blockIdx.y, b = blockIdx.z;
    const size_t ln8 = (size_t)lane * 8;
    const f16* bb = o1_blk + ((size_t)b * NIT + (j0 >> 4) + w) * 8 * 512 + ln8;
    const f16* ab = Wg_blk + (size_t)oh * 8 * 8 * 512 + ln8;

    f32x4 acc[8];
    #pragma unroll
    for (int ot = 0; ot < 8; ++ot) acc[ot] = (f32x4){0.f, 0.f, 0.f, 0.f};

    #pragma unroll
    for (int cc = 0; cc < 8; ++cc) {
        f16x8 bf = *(const f16x8*)(bb + (size_t)cc * 512);
        #pragma unroll
        for (int ot = 0; ot < 8; ++ot) {
            f16x8 af = *(const f16x8*)(ab + ((size_t)ot * 8 + cc) * 512);
            acc[ot] = __builtin_amdgcn_mfma_f32_16x16x32_f16(af, bf, acc[ot], 0, 0, 0);
        }
    }

    const int j = j0 + w * 16 + l16;
    #pragma unroll
    for (int ot = 0; ot < 8; ++ot) {
        int ob = oh * 128 + ot * 16 + quad * 4;
        #pragma unroll
        for (int r = 0; r < 4; ++r)
            out[((size_t)b * CIN + ob + r) * NPIX + j] = acc[ot][r] + gbias[ob + r];
    }
}

// ---------------------------------------------------------------------------
extern "C" void kernel_launch(void* const* d_in, const int* in_sizes, int n_in,
                              void* d_out, int out_size, void* d_ws, size_t ws_size,
                              hipStream_t stream) {
    const float* x   = (const float*)d_in[0];
    const float* qw  = (const float*)d_in[1];
    const float* qbv = (const float*)d_in[2];
    const float* kw  = (const float*)d_in[3];
    const float* kbv = (const float*)d_in[4];
    const float* vw  = (const float*)d_in[5];
    const float* vbv = (const float*)d_in[6];
    const float* gw  = (const float*)d_in[7];
    const float* gbv = (const float*)d_in[8];
    float* out = (float*)d_out;

    const size_t BCN  = (size_t)BATCH * CIN * NPIX;   // 4,718,592
    const size_t BN   = (size_t)BATCH * NPIX;         // 18,432
    const size_t BNCK = (size_t)BATCH * NPIX * CKD;   // 1,179,648

    // ws layout (~36 MB)
    f16* q_blk  = (f16*)d_ws;          // 2.36 MB
    f16* k_blk  = q_blk + BNCK;        // 2.36 MB
    f16* u_blk  = k_blk + BNCK;        // 9.44 MB
    f16* xT     = u_blk + BCN;         // 9.44 MB
    f16* o1_blk = xT + BCN;            // 9.44 MB
    f16* Wqk    = o1_blk + BCN;
    f16* Wv     = Wqk + 128 * 256;
    f16* Wg_blk = Wv + 256 * 256;
    float* S    = (float*)(Wg_blk + 256 * 256);   // 0.07 MB
    float* Pred = S + BN;                          // 2.65 MB

    cast_w<<<96, 256, 0, stream>>>(qw, kw, vw, Wqk, Wv);
    cast_wg<<<32, 256, 0, stream>>>(gw, Wg_blk);
    cast_xT<<<dim3(NPIX / 64, CIN / 64, BATCH), 256, 0, stream>>>(x, xT);
    qk_conv_mfma<<<dim3(NPIX / 32, BATCH), 256, 0, stream>>>(xT, Wqk, qbv, kbv, q_blk, k_blk);
    energy_S<<<dim3(NPIX / 64, NPIX / 128, BATCH), 256, 0, stream>>>(q_blk, k_blk, Pred);
    reduce_S<<<(int)(BN / 256), 256, 0, stream>>>(Pred, S);
    v_conv_mfma<<<dim3(NPIX / 64, CIN / 128, BATCH), 256, 0, stream>>>(xT, Wv, vbv, S, u_blk);
    fused_bmm<<<dim3(NPIX / 32, 2, BATCH), 256, 0, stream>>>(q_blk, k_blk, u_blk, o1_blk);
    gamma_conv_mfma<<<dim3(NPIX / 64, 2, BATCH), 256, 0, stream>>>(o1_blk, Wg_blk, gbv, out);
}